// Round 11
// baseline (561.815 us; speedup 1.0000x reference)
//
#include <hip/hip_runtime.h>
#include <math.h>

#define HD 128
#define PB 256   // partition blocks for bucketed sorts
#define SCB 4096 // elements per block in multi-block scan

typedef __attribute__((ext_vector_type(8))) short short8;
typedef __attribute__((ext_vector_type(4))) float f32x4;

__device__ __forceinline__ float sigf(float v) { return 1.0f / (1.0f + __expf(-v)); }

__device__ __forceinline__ unsigned short f2bf(float f) {
  union { float f; unsigned u; } v; v.f = f;
  unsigned r = (v.u + 0x7fffu + ((v.u >> 16) & 1u)) >> 16;
  return (unsigned short)r;
}
__device__ __forceinline__ float bf2f(unsigned short b) {
  union { unsigned u; float f; } v; v.u = ((unsigned)b) << 16;
  return v.f;
}
__device__ __forceinline__ int clampN(int v, int N) {
  unsigned u = (unsigned)v;
  return (u < (unsigned)N) ? v : (int)(N - 1);
}

// ---------------- pass S: bucket-sort edges by src ----------------

// histogram per (partition-block, src-bucket): cntbuf[bucket*PB + blk]
__global__ __launch_bounds__(256) void scount_k(const int* __restrict__ ei,
                                                int* __restrict__ cntbuf,
                                                int E, int N, int shift, int NB) {
  __shared__ int h[256];
  const int blk = blockIdx.x, tid = threadIdx.x;
  h[tid] = 0;
  __syncthreads();
  int per = (E + PB - 1) / PB;
  int lo = blk * per;
  int hi = (lo + per < E) ? lo + per : E;
  for (int e = lo + tid; e < hi; e += 256) {
    int s = clampN(ei[e], N);
    atomicAdd(&h[s >> shift], 1);
  }
  __syncthreads();
  if (tid < NB) cntbuf[tid * PB + blk] = h[tid];
}

// partition edges into ebuf1 (int2 s,d) grouped by src-bucket
__global__ __launch_bounds__(256) void spart_k(const int* __restrict__ ei,
                                               const int* __restrict__ bstart,
                                               int2* __restrict__ ebuf1,
                                               int E, int N, int shift, int NB) {
  __shared__ int cur[256];
  const int blk = blockIdx.x, tid = threadIdx.x;
  if (tid < NB) cur[tid] = bstart[tid * PB + blk];
  __syncthreads();
  int per = (E + PB - 1) / PB;
  int lo = blk * per;
  int hi = (lo + per < E) ? lo + per : E;
  for (int e = lo + tid; e < hi; e += 256) {
    int s = clampN(ei[e], N);
    int d = clampN(ei[(size_t)E + e], N);
    int p = atomicAdd(&cur[s >> shift], 1);
    ebuf1[p] = make_int2(s, d);
  }
}

// ---------------- multi-block exclusive scan ----------------

__global__ __launch_bounds__(256) void scan1_k(const int* __restrict__ a,
                                               int* __restrict__ bsums, int total) {
  __shared__ int ts[256];
  int b = blockIdx.x, tid = threadIdx.x;
  int lo = b * SCB + tid * 16;
  int s = 0;
#pragma unroll
  for (int i = 0; i < 16; ++i) {
    int idx = lo + i;
    if (idx < total) s += a[idx];
  }
  ts[tid] = s;
  __syncthreads();
  for (int off = 128; off > 0; off >>= 1) {
    if (tid < off) ts[tid] += ts[tid + off];
    __syncthreads();
  }
  if (tid == 0) bsums[b] = ts[0];
}

__global__ __launch_bounds__(256) void scan2_k(int* __restrict__ bsums, int nb) {
  __shared__ int ts[256];
  int tid = threadIdx.x;
  int v = (tid < nb) ? bsums[tid] : 0;
  ts[tid] = v;
  __syncthreads();
  for (int off = 1; off < 256; off <<= 1) {
    int u = (tid >= off) ? ts[tid - off] : 0;
    __syncthreads();
    ts[tid] += u;
    __syncthreads();
  }
  if (tid < nb) bsums[tid] = ts[tid] - v;  // exclusive
}

__global__ __launch_bounds__(256) void scan3_k(int* __restrict__ a,
                                               const int* __restrict__ bsums,
                                               int total, int nblk) {
  __shared__ int ts[256];
  int b = blockIdx.x, tid = threadIdx.x;
  int lo = b * SCB + tid * 16;
  int pre[16];
  int s = 0;
#pragma unroll
  for (int i = 0; i < 16; ++i) {
    int idx = lo + i;
    int xv = (idx < total) ? a[idx] : 0;
    pre[i] = s;
    s += xv;
  }
  ts[tid] = s;
  __syncthreads();
  for (int off = 1; off < 256; off <<= 1) {
    int u = (tid >= off) ? ts[tid - off] : 0;
    __syncthreads();
    ts[tid] += u;
    __syncthreads();
  }
  int off0 = ts[tid] - s + bsums[b];
#pragma unroll
  for (int i = 0; i < 16; ++i) {
    int idx = lo + i;
    if (idx < total) a[idx] = off0 + pre[i];
  }
  if (b == nblk - 1 && tid == 255) a[total] = off0 + s;  // grand total
}

// ---------------- pass D: bucket-sort (src-sorted) edges by dst ----------------

// histogram per (partition-block, dst-bucket) from ebuf1
__global__ __launch_bounds__(256) void bcount2_k(const int2* __restrict__ ebuf1,
                                                 int* __restrict__ cntbuf,
                                                 int E, int shift, int NB) {
  __shared__ int h[256];
  const int blk = blockIdx.x, tid = threadIdx.x;
  h[tid] = 0;
  __syncthreads();
  int per = (E + PB - 1) / PB;
  int lo = blk * per;
  int hi = (lo + per < E) ? lo + per : E;
  for (int e = lo + tid; e < hi; e += 256)
    atomicAdd(&h[ebuf1[e].y >> shift], 1);
  __syncthreads();
  if (tid < NB) cntbuf[tid * PB + blk] = h[tid];
}

// partition ebuf1 into ebuf2 packed (dlocal<<sbits)|src, grouped by dst-bucket.
// block segments are consecutive in ebuf1 -> src-window order preserved per run.
__global__ __launch_bounds__(256) void bpart2_k(const int2* __restrict__ ebuf1,
                                                const int* __restrict__ bstart,
                                                unsigned* __restrict__ ebuf2,
                                                int E, int shift, int NB, int sbits) {
  __shared__ int cur[256];
  const int blk = blockIdx.x, tid = threadIdx.x;
  if (tid < NB) cur[tid] = bstart[tid * PB + blk];
  __syncthreads();
  int per = (E + PB - 1) / PB;
  int lo = blk * per;
  int hi = (lo + per < E) ? lo + per : E;
  const unsigned dmask = (1u << shift) - 1u;
  for (int e = lo + tid; e < hi; e += 256) {
    int2 sd = ebuf1[e];
    int p = atomicAdd(&cur[sd.y >> shift], 1);
    ebuf2[p] = (((unsigned)sd.y & dmask) << sbits) | (unsigned)sd.x;
  }
}

// pass F: per-bucket: count per-dst in LDS, LDS-scan -> rowstart, place edges.
__global__ __launch_bounds__(256) void bfill2_k(const unsigned* __restrict__ ebuf2,
                                                const int* __restrict__ bstart,
                                                int* __restrict__ rowstart,
                                                int* __restrict__ csr,
                                                int N, int shift, int NB, int sbits) {
  __shared__ int cnt[2048];
  __shared__ int tsum[256];
  const int b = blockIdx.x, tid = threadIdx.x;
  const int d0 = b << shift;
  int dmax = d0 + (1 << shift);
  if (dmax > N) dmax = N;
  const int nd = dmax - d0;
  const unsigned smask = (1u << sbits) - 1u;
  for (int i = tid; i < nd; i += 256) cnt[i] = 0;
  __syncthreads();
  const int base = bstart[b * PB];
  const int end = bstart[(b + 1) * PB];  // b=NB-1 -> bstart[NB*PB] = grand total
  for (int idx = base + tid; idx < end; idx += 256)
    atomicAdd(&cnt[ebuf2[idx] >> sbits], 1);
  __syncthreads();
  const int C = (nd + 255) / 256;  // <= 8
  int lo = tid * C;
  int hi = (lo + C < nd) ? lo + C : nd;
  int loc[8];
  int s = 0;
  for (int i = lo; i < hi; ++i) {
    loc[i - lo] = cnt[i];
    s += cnt[i];
  }
  tsum[tid] = s;
  __syncthreads();
  for (int off = 1; off < 256; off <<= 1) {
    int u = (tid >= off) ? tsum[tid - off] : 0;
    __syncthreads();
    tsum[tid] += u;
    __syncthreads();
  }
  int run = tsum[tid] - s + base;
  for (int i = lo; i < hi; ++i) {
    rowstart[d0 + i] = run;
    cnt[i] = run;  // becomes the cursor
    run += loc[i - lo];
  }
  if (b == NB - 1 && tid == 255) rowstart[N] = end;
  __syncthreads();
  for (int idx = base + tid; idx < end; idx += 256) {
    unsigned pk = ebuf2[idx];
    int p = atomicAdd(&cnt[pk >> sbits], 1);
    csr[p] = (int)(pk & smask);
  }
}

// ---------------- conversions ----------------

__global__ __launch_bounds__(256) void convx_k(const float* __restrict__ x,
                                               unsigned short* __restrict__ xb, int n4) {
  int t = blockIdx.x * 256 + threadIdx.x;
  if (t >= n4) return;
  float4 v = reinterpret_cast<const float4*>(x)[t];
  ushort4 o;
  o.x = f2bf(v.x); o.y = f2bf(v.y); o.z = f2bf(v.z); o.w = f2bf(v.w);
  reinterpret_cast<ushort4*>(xb)[t] = o;
}

__global__ __launch_bounds__(256) void prepw_k(
    const float* __restrict__ W, const float* __restrict__ gwih,
    const float* __restrict__ gwhh, const float* __restrict__ lwih,
    const float* __restrict__ lbih, const float* __restrict__ lbhh,
    unsigned short* __restrict__ Wt, unsigned short* __restrict__ gwihb,
    unsigned short* __restrict__ gwhhb, unsigned short* __restrict__ lwb,
    float* __restrict__ lbias) {
  int t = blockIdx.x * 256 + threadIdx.x;
  if (t < 16384) {  // Wt[n][k] = W[k][n]
    int n = t >> 7, k = t & 127;
    Wt[t] = f2bf(W[(size_t)k * 128 + n]);
    return;
  }
  t -= 16384;
  if (t < 49152) { gwihb[t] = f2bf(gwih[t]); return; }
  t -= 49152;
  if (t < 49152) { gwhhb[t] = f2bf(gwhh[t]); return; }
  t -= 49152;
  if (t < 49152) {  // select i,g,o rows of [512,128]
    int j = t >> 7, k = t & 127;
    int jm = j < 128 ? j : j + 128;
    lwb[t] = f2bf(lwih[(size_t)jm * 128 + k]);
    return;
  }
  t -= 49152;
  if (t < 384) {
    int jm = t < 128 ? t : t + 128;
    lbias[t] = lbih[jm] + lbhh[jm];
  }
}

// ---------------- gather (bf16 in, bf16 out) ----------------
// wave = 4 subgroups of 16 lanes; each subgroup covers one edge row with uint4.
// Lists are src-sorted (bucket granularity) -> concurrent waves sweep the src
// space in near-lockstep -> hot window stays L2-resident.
__global__ __launch_bounds__(256) void gather_b_k(const int* __restrict__ csr,
                                                  const int* __restrict__ rowstart,
                                                  const unsigned short* __restrict__ xb,
                                                  unsigned short* __restrict__ xaggb, int N) {
  int w = (int)(((long long)blockIdx.x * 256 + threadIdx.x) >> 6);
  if (w >= N) return;
  const int lane = threadIdx.x & 63;
  const int sub = lane >> 4, li = lane & 15;
  const int beg = rowstart[w], end = rowstart[w + 1];
  const uint4* x4 = reinterpret_cast<const uint4*>(xb);  // row = 16 uint4

  float acc[8] = {0.f, 0.f, 0.f, 0.f, 0.f, 0.f, 0.f, 0.f};

  int j = beg;
  for (; j + 8 <= end; j += 8) {
    int s0 = csr[j + sub];
    int s1 = csr[j + 4 + sub];
    uint4 v0 = x4[(size_t)s0 * 16 + li];
    uint4 v1 = x4[(size_t)s1 * 16 + li];
    acc[0] += bf2f((unsigned short)v0.x) + bf2f((unsigned short)v1.x);
    acc[1] += bf2f((unsigned short)(v0.x >> 16)) + bf2f((unsigned short)(v1.x >> 16));
    acc[2] += bf2f((unsigned short)v0.y) + bf2f((unsigned short)v1.y);
    acc[3] += bf2f((unsigned short)(v0.y >> 16)) + bf2f((unsigned short)(v1.y >> 16));
    acc[4] += bf2f((unsigned short)v0.z) + bf2f((unsigned short)v1.z);
    acc[5] += bf2f((unsigned short)(v0.z >> 16)) + bf2f((unsigned short)(v1.z >> 16));
    acc[6] += bf2f((unsigned short)v0.w) + bf2f((unsigned short)v1.w);
    acc[7] += bf2f((unsigned short)(v0.w >> 16)) + bf2f((unsigned short)(v1.w >> 16));
  }
  if (j + 4 <= end) {
    int s0 = csr[j + sub];
    uint4 v0 = x4[(size_t)s0 * 16 + li];
    acc[0] += bf2f((unsigned short)v0.x);
    acc[1] += bf2f((unsigned short)(v0.x >> 16));
    acc[2] += bf2f((unsigned short)v0.y);
    acc[3] += bf2f((unsigned short)(v0.y >> 16));
    acc[4] += bf2f((unsigned short)v0.z);
    acc[5] += bf2f((unsigned short)(v0.z >> 16));
    acc[6] += bf2f((unsigned short)v0.w);
    acc[7] += bf2f((unsigned short)(v0.w >> 16));
    j += 4;
  }
  int rem = end - j;  // 0..3
  if (sub < rem) {
    int s0 = csr[j + sub];
    uint4 v0 = x4[(size_t)s0 * 16 + li];
    acc[0] += bf2f((unsigned short)v0.x);
    acc[1] += bf2f((unsigned short)(v0.x >> 16));
    acc[2] += bf2f((unsigned short)v0.y);
    acc[3] += bf2f((unsigned short)(v0.y >> 16));
    acc[4] += bf2f((unsigned short)v0.z);
    acc[5] += bf2f((unsigned short)(v0.z >> 16));
    acc[6] += bf2f((unsigned short)v0.w);
    acc[7] += bf2f((unsigned short)(v0.w >> 16));
  }

#pragma unroll
  for (int i = 0; i < 8; ++i) {
    acc[i] += __shfl_xor(acc[i], 16, 64);
    acc[i] += __shfl_xor(acc[i], 32, 64);
  }

  if (lane < 16) {
    float scale = 1.0f / fmaxf((float)(end - beg), 1.0f);
    uint4 o;
    o.x = (unsigned)f2bf(acc[0] * scale) | ((unsigned)f2bf(acc[1] * scale) << 16);
    o.y = (unsigned)f2bf(acc[2] * scale) | ((unsigned)f2bf(acc[3] * scale) << 16);
    o.z = (unsigned)f2bf(acc[4] * scale) | ((unsigned)f2bf(acc[5] * scale) << 16);
    o.w = (unsigned)f2bf(acc[6] * scale) | ((unsigned)f2bf(acc[7] * scale) << 16);
    reinterpret_cast<uint4*>(xaggb)[(size_t)w * 16 + li] = o;
  }
}

// ---------------- W GEMM (bf16 NT, K=128, bf16 out) ----------------
__global__ __launch_bounds__(256) void gemmw_k(const unsigned short* __restrict__ A,
                                               const unsigned short* __restrict__ B,
                                               unsigned short* __restrict__ C, int nrows) {
  __shared__ unsigned short Bs[64][136];
  const int tid = threadIdx.x;
  const int w = tid >> 6, lane = tid & 63;
  const int q = lane >> 4, r = lane & 15;
  const int row0 = blockIdx.y * 64;
  const int col0 = blockIdx.x * 64;

#pragma unroll
  for (int i = 0; i < 4; ++i) {
    int idx = i * 256 + tid;
    int c = idx >> 4, kq = idx & 15;
    uint4 v = *reinterpret_cast<const uint4*>(&B[((size_t)(col0 + c)) * HD + kq * 8]);
    *reinterpret_cast<uint4*>(&Bs[c][kq * 8]) = v;
  }
  __syncthreads();

  int arow = row0 + (w << 4) + r;
  int ar = arow < nrows ? arow : nrows - 1;
  const unsigned short* Ap = A + (size_t)ar * HD + q * 8;

  f32x4 acc[4];
#pragma unroll
  for (int cb = 0; cb < 4; ++cb) acc[cb] = (f32x4)0.f;

#pragma unroll
  for (int ks = 0; ks < 4; ++ks) {
    short8 af = *reinterpret_cast<const short8*>(Ap + ks * 32);
#pragma unroll
    for (int cb = 0; cb < 4; ++cb) {
      short8 bf = *reinterpret_cast<const short8*>(&Bs[cb * 16 + r][ks * 32 + q * 8]);
      acc[cb] = __builtin_amdgcn_mfma_f32_16x16x32_bf16(af, bf, acc[cb], 0, 0, 0);
    }
  }

#pragma unroll
  for (int cb = 0; cb < 4; ++cb) {
    int col = col0 + cb * 16 + r;
#pragma unroll
    for (int reg = 0; reg < 4; ++reg) {
      int row = row0 + (w << 4) + q * 4 + reg;
      if (row < nrows) C[(size_t)row * HD + col] = f2bf(acc[cb][reg]);
    }
  }
}

// ---------------- fused GRU ----------------
__global__ __launch_bounds__(256) void gru_fused_k(
    const unsigned short* __restrict__ Acb, const unsigned short* __restrict__ xb,
    const unsigned short* __restrict__ gwihb, const unsigned short* __restrict__ gwhhb,
    const float* __restrict__ gbih, const float* __restrict__ gbhh,
    unsigned short* __restrict__ hconv, int nrows) {
  __shared__ unsigned short Bsm[6][32][136];
  const int tid = threadIdx.x;
  const int w = tid >> 6, lane = tid & 63;
  const int q = lane >> 4, r = lane & 15;
  const int row0 = blockIdx.y * 64;
  const int c0 = blockIdx.x * 32;

#pragma unroll
  for (int it = 0; it < 12; ++it) {
    int idx = it * 256 + tid;
    int p = idx >> 9;
    int rem = idx & 511;
    int col = rem >> 4, kq = rem & 15;
    const unsigned short* src =
        (p < 3) ? gwihb + ((size_t)(p * 128 + c0 + col)) * HD
                : gwhhb + ((size_t)((p - 3) * 128 + c0 + col)) * HD;
    uint4 v = *reinterpret_cast<const uint4*>(src + kq * 8);
    *reinterpret_cast<uint4*>(&Bsm[p][col][kq * 8]) = v;
  }
  __syncthreads();

  int arow = row0 + (w << 4) + r;
  int ar = arow < nrows ? arow : nrows - 1;
  const unsigned short* Aa = Acb + (size_t)ar * HD + q * 8;
  const unsigned short* Ax = xb + (size_t)ar * HD + q * 8;

  f32x4 acc[6][2];
#pragma unroll
  for (int p = 0; p < 6; ++p)
#pragma unroll
    for (int cb = 0; cb < 2; ++cb) acc[p][cb] = (f32x4)0.f;

#pragma unroll
  for (int ks = 0; ks < 4; ++ks) {
    short8 a1 = *reinterpret_cast<const short8*>(Aa + ks * 32);
    short8 a2 = *reinterpret_cast<const short8*>(Ax + ks * 32);
#pragma unroll
    for (int p = 0; p < 6; ++p) {
      short8 af = (p < 3) ? a1 : a2;
#pragma unroll
      for (int cb = 0; cb < 2; ++cb) {
        short8 bf = *reinterpret_cast<const short8*>(&Bsm[p][cb * 16 + r][ks * 32 + q * 8]);
        acc[p][cb] = __builtin_amdgcn_mfma_f32_16x16x32_bf16(af, bf, acc[p][cb], 0, 0, 0);
      }
    }
  }

#pragma unroll
  for (int cb = 0; cb < 2; ++cb) {
    int col = c0 + cb * 16 + r;
    float bir = gbih[col], biz = gbih[col + 128], bin = gbih[col + 256];
    float bhr = gbhh[col], bhz = gbhh[col + 128], bhn = gbhh[col + 256];
#pragma unroll
    for (int reg = 0; reg < 4; ++reg) {
      int row = row0 + (w << 4) + q * 4 + reg;
      if (row < nrows) {
        float ir = acc[0][cb][reg] + bir, iz = acc[1][cb][reg] + biz;
        float inn = acc[2][cb][reg] + bin;
        float hr = acc[3][cb][reg] + bhr, hz = acc[4][cb][reg] + bhz;
        float hn = acc[5][cb][reg] + bhn;
        float rr = sigf(ir + hr), zz = sigf(iz + hz);
        float nn = tanhf(inn + rr * hn);
        float xv = bf2f(xb[(size_t)row * HD + col]);
        hconv[(size_t)row * HD + col] = f2bf((1.f - zz) * nn + zz * xv);
      }
    }
  }
}

// ---------------- fused LSTM ----------------
__global__ __launch_bounds__(256) void lstm_fused_k(
    const unsigned short* __restrict__ hconv, const unsigned short* __restrict__ lwb,
    const float* __restrict__ lbias, float* __restrict__ out, int nrows) {
  __shared__ unsigned short Bsm[3][64][136];
  const int tid = threadIdx.x;
  const int w = tid >> 6, lane = tid & 63;
  const int q = lane >> 4, r = lane & 15;
  const int row0 = blockIdx.y * 64;
  const int c0 = blockIdx.x * 64;

#pragma unroll
  for (int it = 0; it < 12; ++it) {
    int idx = it * 256 + tid;
    int p = idx >> 10, rem = idx & 1023;
    int col = rem >> 4, kq = rem & 15;
    uint4 v = *reinterpret_cast<const uint4*>(
        lwb + ((size_t)(p * 128 + c0 + col)) * HD + kq * 8);
    *reinterpret_cast<uint4*>(&Bsm[p][col][kq * 8]) = v;
  }
  __syncthreads();

  int arow = row0 + (w << 4) + r;
  int ar = arow < nrows ? arow : nrows - 1;
  const unsigned short* Ap = hconv + (size_t)ar * HD + q * 8;

  f32x4 acc[3][4];
#pragma unroll
  for (int p = 0; p < 3; ++p)
#pragma unroll
    for (int cb = 0; cb < 4; ++cb) acc[p][cb] = (f32x4)0.f;

#pragma unroll
  for (int ks = 0; ks < 4; ++ks) {
    short8 af = *reinterpret_cast<const short8*>(Ap + ks * 32);
#pragma unroll
    for (int p = 0; p < 3; ++p)
#pragma unroll
      for (int cb = 0; cb < 4; ++cb) {
        short8 bf = *reinterpret_cast<const short8*>(&Bsm[p][cb * 16 + r][ks * 32 + q * 8]);
        acc[p][cb] = __builtin_amdgcn_mfma_f32_16x16x32_bf16(af, bf, acc[p][cb], 0, 0, 0);
      }
  }

#pragma unroll
  for (int cb = 0; cb < 4; ++cb) {
    int col = c0 + cb * 16 + r;
    float bi = lbias[col], bg = lbias[col + 128], bo = lbias[col + 256];
#pragma unroll
    for (int reg = 0; reg < 4; ++reg) {
      int row = row0 + (w << 4) + q * 4 + reg;
      if (row < nrows) {
        float ig = acc[0][cb][reg] + bi;
        float gg = acc[1][cb][reg] + bg;
        float og = acc[2][cb][reg] + bo;
        float cc = sigf(ig) * tanhf(gg);
        out[(size_t)row * HD + col] = fmaxf(sigf(og) * tanhf(cc), 0.f);
      }
    }
  }
}

// ---------------- host ----------------

extern "C" void kernel_launch(void* const* d_in, const int* in_sizes, int n_in,
                              void* d_out, int out_size, void* d_ws, size_t ws_size,
                              hipStream_t stream) {
  const float* x = (const float*)d_in[0];
  const int* ei = (const int*)d_in[1];
  const float* W = (const float*)d_in[2];
  const float* gw_ih = (const float*)d_in[3];
  const float* gw_hh = (const float*)d_in[4];
  const float* gb_ih = (const float*)d_in[5];
  const float* gb_hh = (const float*)d_in[6];
  const float* lw_ih = (const float*)d_in[7];
  const float* lb_ih = (const float*)d_in[9];
  const float* lb_hh = (const float*)d_in[10];
  float* out = (float*)d_out;

  const int N = in_sizes[0] / HD;
  const int E = in_sizes[1] / 2;
  const size_t nH = (size_t)N * HD;

  int shift = 9;
  while (((N + (1 << shift) - 1) >> shift) > 256) ++shift;
  const int NB = (N + (1 << shift) - 1) >> shift;
  const int sbits = 32 - shift;  // src bits in packed ebuf2

  const size_t N4p = (size_t)((N + 1 + 7) & ~7);  // rowstart: N+1
  const size_t E4 = (size_t)((E + 3) & ~3);
  const size_t BC = (size_t)NB * PB + 8;
  const int sc_total = NB * PB;
  const int sc_nblk = (sc_total + SCB - 1) / SCB;

  // ws layout: [rowstart][bcnt][bsums][csr][ebuf2][ebuf1|xb][Acb][hconv][weights]
  char* p = (char*)d_ws;
  int* rowstart = (int*)p;  p += 4 * N4p;
  int* bcnt = (int*)p;      p += 4 * BC;   // reused for src pass then dst pass
  int* bsums = (int*)p;     p += 4 * 64;
  int* csr = (int*)p;       p += 4 * E4;
  unsigned* ebuf2 = (unsigned*)p; p += 4 * E4;
  size_t sz_eb1 = 8 * E4, sz_xb = 2 * nH;
  int2* ebuf1 = (int2*)p;                   // dead after bpart2_k
  unsigned short* xb = (unsigned short*)p;  // written by convx_k after
  p += (sz_eb1 > sz_xb ? sz_eb1 : sz_xb);
  unsigned short* Acb = (unsigned short*)p;    p += 2 * nH;
  unsigned short* hconv = (unsigned short*)p;  p += 2 * nH;
  unsigned short* Wt = (unsigned short*)p;     p += 2 * 16384;
  unsigned short* gwihb = (unsigned short*)p;  p += 2 * 49152;
  unsigned short* gwhhb = (unsigned short*)p;  p += 2 * 49152;
  unsigned short* lwb = (unsigned short*)p;    p += 2 * 49152;
  float* lbias = (float*)p;                    p += 4 * 384;

  unsigned short* xaggb = (unsigned short*)d_out;  // consumed before out written

  dim3 blk(256);
  unsigned rb = (unsigned)((N + 63) / 64);

  // ---- pass S: sort edges by src bucket (512-row windows) ----
  scount_k<<<PB, blk, 0, stream>>>(ei, bcnt, E, N, shift, NB);
  scan1_k<<<sc_nblk, blk, 0, stream>>>(bcnt, bsums, sc_total);
  scan2_k<<<1, blk, 0, stream>>>(bsums, sc_nblk);
  scan3_k<<<sc_nblk, blk, 0, stream>>>(bcnt, bsums, sc_total, sc_nblk);
  spart_k<<<PB, blk, 0, stream>>>(ei, bcnt, ebuf1, E, N, shift, NB);

  // ---- pass D: sort src-sorted edges by dst bucket (order-preserving runs) ----
  bcount2_k<<<PB, blk, 0, stream>>>(ebuf1, bcnt, E, shift, NB);
  scan1_k<<<sc_nblk, blk, 0, stream>>>(bcnt, bsums, sc_total);
  scan2_k<<<1, blk, 0, stream>>>(bsums, sc_nblk);
  scan3_k<<<sc_nblk, blk, 0, stream>>>(bcnt, bsums, sc_total, sc_nblk);
  bpart2_k<<<PB, blk, 0, stream>>>(ebuf1, bcnt, ebuf2, E, shift, NB, sbits);
  bfill2_k<<<NB, blk, 0, stream>>>(ebuf2, bcnt, rowstart, csr, N, shift, NB, sbits);

  // conversions (xb overwrites ebuf1 - dead after bpart2)
  convx_k<<<(unsigned)((nH / 4 + 255) / 256), blk, 0, stream>>>(x, xb, (int)(nH / 4));
  prepw_k<<<(16384 + 3 * 49152 + 384 + 255) / 256, blk, 0, stream>>>(
      W, gw_ih, gw_hh, lw_ih, lb_ih, lb_hh, Wt, gwihb, gwhhb, lwb, lbias);

  // aggregation (src-swept)
  long long gthreads = (long long)N * 64;
  gather_b_k<<<(unsigned)((gthreads + 255) / 256), blk, 0, stream>>>(
      csr, rowstart, xb, xaggb, N);

  // Ac = xagg @ W
  gemmw_k<<<dim3(2, rb), blk, 0, stream>>>(xaggb, Wt, Acb, N);

  // hconv = GRU(Ac, x)
  gru_fused_k<<<dim3(4, rb), blk, 0, stream>>>(
      Acb, xb, gwihb, gwhhb, gb_ih, gb_hh, hconv, N);

  // out = LSTM(hconv)
  lstm_fused_k<<<dim3(2, rb), blk, 0, stream>>>(hconv, lwb, lbias, out, N);
}

// Round 12
// 500.158 us; speedup vs baseline: 1.1233x; 1.1233x over previous
//
#include <hip/hip_runtime.h>
#include <math.h>

#define HD 128
#define PB 256   // partition blocks for bucketed CSR build
#define SCB 4096 // elements per block in multi-block scan

typedef __attribute__((ext_vector_type(8))) short short8;
typedef __attribute__((ext_vector_type(4))) float f32x4;

__device__ __forceinline__ float sigf(float v) { return 1.0f / (1.0f + __expf(-v)); }

__device__ __forceinline__ unsigned short f2bf(float f) {
  union { float f; unsigned u; } v; v.f = f;
  unsigned r = (v.u + 0x7fffu + ((v.u >> 16) & 1u)) >> 16;
  return (unsigned short)r;
}
__device__ __forceinline__ float bf2f(unsigned short b) {
  union { unsigned u; float f; } v; v.u = ((unsigned)b) << 16;
  return v.f;
}

// ---------------- CSR build (round-10 structure) ----------------

__global__ __launch_bounds__(256) void bcount_k(const int* __restrict__ ei,
                                                int* __restrict__ bcnt,
                                                int E, int N, int shift, int NB) {
  __shared__ int h[256];
  const int blk = blockIdx.x, tid = threadIdx.x;
  h[tid] = 0;
  __syncthreads();
  int per = (E + PB - 1) / PB;
  int lo = blk * per;
  int hi = (lo + per < E) ? lo + per : E;
  for (int e = lo + tid; e < hi; e += 256) {
    int d = ei[(size_t)E + e];
    if ((unsigned)d >= (unsigned)N) continue;
    atomicAdd(&h[d >> shift], 1);
  }
  __syncthreads();
  if (tid < NB) bcnt[tid * PB + blk] = h[tid];
}

__global__ __launch_bounds__(256) void scan1_k(const int* __restrict__ a,
                                               int* __restrict__ bsums, int total) {
  __shared__ int ts[256];
  int b = blockIdx.x, tid = threadIdx.x;
  int lo = b * SCB + tid * 16;
  int s = 0;
#pragma unroll
  for (int i = 0; i < 16; ++i) {
    int idx = lo + i;
    if (idx < total) s += a[idx];
  }
  ts[tid] = s;
  __syncthreads();
  for (int off = 128; off > 0; off >>= 1) {
    if (tid < off) ts[tid] += ts[tid + off];
    __syncthreads();
  }
  if (tid == 0) bsums[b] = ts[0];
}

__global__ __launch_bounds__(256) void scan2_k(int* __restrict__ bsums, int nb) {
  __shared__ int ts[256];
  int tid = threadIdx.x;
  int v = (tid < nb) ? bsums[tid] : 0;
  ts[tid] = v;
  __syncthreads();
  for (int off = 1; off < 256; off <<= 1) {
    int u = (tid >= off) ? ts[tid - off] : 0;
    __syncthreads();
    ts[tid] += u;
    __syncthreads();
  }
  if (tid < nb) bsums[tid] = ts[tid] - v;  // exclusive
}

__global__ __launch_bounds__(256) void scan3_k(int* __restrict__ a,
                                               const int* __restrict__ bsums,
                                               int total, int nblk) {
  __shared__ int ts[256];
  int b = blockIdx.x, tid = threadIdx.x;
  int lo = b * SCB + tid * 16;
  int pre[16];
  int s = 0;
#pragma unroll
  for (int i = 0; i < 16; ++i) {
    int idx = lo + i;
    int xv = (idx < total) ? a[idx] : 0;
    pre[i] = s;
    s += xv;
  }
  ts[tid] = s;
  __syncthreads();
  for (int off = 1; off < 256; off <<= 1) {
    int u = (tid >= off) ? ts[tid - off] : 0;
    __syncthreads();
    ts[tid] += u;
    __syncthreads();
  }
  int off0 = ts[tid] - s + bsums[b];
#pragma unroll
  for (int i = 0; i < 16; ++i) {
    int idx = lo + i;
    if (idx < total) a[idx] = off0 + pre[i];
  }
  if (b == nblk - 1 && tid == 255) a[total] = off0 + s;  // grand total
}

__global__ __launch_bounds__(256) void bpart_k(const int* __restrict__ ei,
                                               const int* __restrict__ bstart,
                                               unsigned* __restrict__ ebuf,
                                               int E, int N, int shift, int NB,
                                               int sbits) {
  __shared__ int cur[256];
  const int blk = blockIdx.x, tid = threadIdx.x;
  if (tid < NB) cur[tid] = bstart[tid * PB + blk];
  __syncthreads();
  int per = (E + PB - 1) / PB;
  int lo = blk * per;
  int hi = (lo + per < E) ? lo + per : E;
  const unsigned dmask = (1u << shift) - 1u;
  for (int e = lo + tid; e < hi; e += 256) {
    int s = ei[e];
    int d = ei[(size_t)E + e];
    if ((unsigned)s >= (unsigned)N || (unsigned)d >= (unsigned)N) continue;
    int p = atomicAdd(&cur[d >> shift], 1);
    ebuf[p] = (((unsigned)d & dmask) << sbits) | (unsigned)s;
  }
}

__global__ __launch_bounds__(256) void bfill2_k(const unsigned* __restrict__ ebuf,
                                                const int* __restrict__ bstart,
                                                int* __restrict__ rowstart,
                                                int* __restrict__ csr,
                                                int N, int shift, int NB, int sbits) {
  __shared__ int cnt[2048];
  __shared__ int tsum[256];
  const int b = blockIdx.x, tid = threadIdx.x;
  const int d0 = b << shift;
  int dmax = d0 + (1 << shift);
  if (dmax > N) dmax = N;
  const int nd = dmax - d0;
  const unsigned smask = (1u << sbits) - 1u;
  for (int i = tid; i < nd; i += 256) cnt[i] = 0;
  __syncthreads();
  const int base = bstart[b * PB];
  const int end = bstart[(b + 1) * PB];  // b=NB-1 -> bstart[NB*PB] = grand total
  for (int idx = base + tid; idx < end; idx += 256)
    atomicAdd(&cnt[ebuf[idx] >> sbits], 1);
  __syncthreads();
  const int C = (nd + 255) / 256;  // <= 8
  int lo = tid * C;
  int hi = (lo + C < nd) ? lo + C : nd;
  int loc[8];
  int s = 0;
  for (int i = lo; i < hi; ++i) {
    loc[i - lo] = cnt[i];
    s += cnt[i];
  }
  tsum[tid] = s;
  __syncthreads();
  for (int off = 1; off < 256; off <<= 1) {
    int u = (tid >= off) ? tsum[tid - off] : 0;
    __syncthreads();
    tsum[tid] += u;
    __syncthreads();
  }
  int run = tsum[tid] - s + base;
  for (int i = lo; i < hi; ++i) {
    rowstart[d0 + i] = run;
    cnt[i] = run;  // becomes the cursor
    run += loc[i - lo];
  }
  if (b == NB - 1 && tid == 255) rowstart[N] = end;
  __syncthreads();
  for (int idx = base + tid; idx < end; idx += 256) {
    unsigned pk = ebuf[idx];
    int p = atomicAdd(&cnt[pk >> sbits], 1);
    csr[p] = (int)(pk & smask);
  }
}

// ---------------- conversions ----------------

__global__ __launch_bounds__(256) void convx_k(const float* __restrict__ x,
                                               unsigned short* __restrict__ xb, int n4) {
  int t = blockIdx.x * 256 + threadIdx.x;
  if (t >= n4) return;
  float4 v = reinterpret_cast<const float4*>(x)[t];
  ushort4 o;
  o.x = f2bf(v.x); o.y = f2bf(v.y); o.z = f2bf(v.z); o.w = f2bf(v.w);
  reinterpret_cast<ushort4*>(xb)[t] = o;
}

// gwhh cast; lw row-select i,g,o; lbias combine
__global__ __launch_bounds__(256) void prepw_k(
    const float* __restrict__ gwhh, const float* __restrict__ lwih,
    const float* __restrict__ lbih, const float* __restrict__ lbhh,
    unsigned short* __restrict__ gwhhb, unsigned short* __restrict__ lwb,
    float* __restrict__ lbias) {
  int t = blockIdx.x * 256 + threadIdx.x;
  if (t < 49152) { gwhhb[t] = f2bf(gwhh[t]); return; }
  t -= 49152;
  if (t < 49152) {  // select i,g,o rows of [512,128]
    int j = t >> 7, k = t & 127;
    int jm = j < 128 ? j : j + 128;
    lwb[t] = f2bf(lwih[(size_t)jm * 128 + k]);
    return;
  }
  t -= 49152;
  if (t < 384) {
    int jm = t < 128 ? t : t + 128;
    lbias[t] = lbih[jm] + lbhh[jm];
  }
}

// Bp[j,k] = sum_c W[k,c] * gwih[j,c]  (fold of conv-W into GRU input weight)
// gi = xagg @ Bp^T + b_ih  ==  ((xagg @ W) @ gwih^T) + b_ih
__global__ __launch_bounds__(256) void prepbp_k(const float* __restrict__ W,
                                                const float* __restrict__ gwih,
                                                unsigned short* __restrict__ Bpb) {
  int t = blockIdx.x * 256 + threadIdx.x;
  if (t >= 49152) return;
  int j = t >> 7, k = t & 127;
  const float4* wr = reinterpret_cast<const float4*>(W + (size_t)k * 128);
  const float4* gr = reinterpret_cast<const float4*>(gwih + (size_t)j * 128);
  float acc = 0.f;
#pragma unroll
  for (int c = 0; c < 32; ++c) {
    float4 a = wr[c], b = gr[c];
    acc += a.x * b.x + a.y * b.y + a.z * b.z + a.w * b.w;
  }
  Bpb[t] = f2bf(acc);
}

// ---------------- gather (bf16 in, bf16 out), 4 loads in flight ----------------
__device__ __forceinline__ void acc8(float* acc, uint4 v) {
  acc[0] += bf2f((unsigned short)v.x);
  acc[1] += bf2f((unsigned short)(v.x >> 16));
  acc[2] += bf2f((unsigned short)v.y);
  acc[3] += bf2f((unsigned short)(v.y >> 16));
  acc[4] += bf2f((unsigned short)v.z);
  acc[5] += bf2f((unsigned short)(v.z >> 16));
  acc[6] += bf2f((unsigned short)v.w);
  acc[7] += bf2f((unsigned short)(v.w >> 16));
}

__global__ __launch_bounds__(256) void gather_b_k(const int* __restrict__ csr,
                                                  const int* __restrict__ rowstart,
                                                  const unsigned short* __restrict__ xb,
                                                  unsigned short* __restrict__ xaggb, int N) {
  int w = (int)(((long long)blockIdx.x * 256 + threadIdx.x) >> 6);
  if (w >= N) return;
  const int lane = threadIdx.x & 63;
  const int sub = lane >> 4, li = lane & 15;
  const int beg = rowstart[w], end = rowstart[w + 1];
  const uint4* x4 = reinterpret_cast<const uint4*>(xb);  // row = 16 uint4

  float acc[8] = {0.f, 0.f, 0.f, 0.f, 0.f, 0.f, 0.f, 0.f};

  int j = beg;
  for (; j + 16 <= end; j += 16) {
    int s0 = csr[j + sub];
    int s1 = csr[j + 4 + sub];
    int s2 = csr[j + 8 + sub];
    int s3 = csr[j + 12 + sub];
    uint4 v0 = x4[(size_t)s0 * 16 + li];
    uint4 v1 = x4[(size_t)s1 * 16 + li];
    uint4 v2 = x4[(size_t)s2 * 16 + li];
    uint4 v3 = x4[(size_t)s3 * 16 + li];
    acc8(acc, v0); acc8(acc, v1); acc8(acc, v2); acc8(acc, v3);
  }
  for (; j + 4 <= end; j += 4) {
    int s0 = csr[j + sub];
    uint4 v0 = x4[(size_t)s0 * 16 + li];
    acc8(acc, v0);
  }
  int rem = end - j;  // 0..3
  if (sub < rem) {
    int s0 = csr[j + sub];
    uint4 v0 = x4[(size_t)s0 * 16 + li];
    acc8(acc, v0);
  }

#pragma unroll
  for (int i = 0; i < 8; ++i) {
    acc[i] += __shfl_xor(acc[i], 16, 64);
    acc[i] += __shfl_xor(acc[i], 32, 64);
  }

  if (lane < 16) {
    float scale = 1.0f / fmaxf((float)(end - beg), 1.0f);
    uint4 o;
    o.x = (unsigned)f2bf(acc[0] * scale) | ((unsigned)f2bf(acc[1] * scale) << 16);
    o.y = (unsigned)f2bf(acc[2] * scale) | ((unsigned)f2bf(acc[3] * scale) << 16);
    o.z = (unsigned)f2bf(acc[4] * scale) | ((unsigned)f2bf(acc[5] * scale) << 16);
    o.w = (unsigned)f2bf(acc[6] * scale) | ((unsigned)f2bf(acc[7] * scale) << 16);
    reinterpret_cast<uint4*>(xaggb)[(size_t)w * 16 + li] = o;
  }
}

// ---------------- fused GRU: hconv = GRU(xagg@Bp^T, x@gwhh^T) ----------------
// grid (4, ceil(nrows/64)); tile 64 rows x 32 cols x 6 planes (ir,iz,in,hr,hz,hn)
__global__ __launch_bounds__(256) void gru_fused_k(
    const unsigned short* __restrict__ xaggb, const unsigned short* __restrict__ xb,
    const unsigned short* __restrict__ Bpb, const unsigned short* __restrict__ gwhhb,
    const float* __restrict__ gbih, const float* __restrict__ gbhh,
    unsigned short* __restrict__ hconv, int nrows) {
  __shared__ unsigned short Bsm[6][32][136];
  const int tid = threadIdx.x;
  const int w = tid >> 6, lane = tid & 63;
  const int q = lane >> 4, r = lane & 15;
  const int row0 = blockIdx.y * 64;
  const int c0 = blockIdx.x * 32;

  // 6 planes x 32 cols x 16 kq = 3072 uint4 (12 x 256)
#pragma unroll
  for (int it = 0; it < 12; ++it) {
    int idx = it * 256 + tid;
    int p = idx >> 9;
    int rem = idx & 511;
    int col = rem >> 4, kq = rem & 15;
    const unsigned short* src =
        (p < 3) ? Bpb + ((size_t)(p * 128 + c0 + col)) * HD
                : gwhhb + ((size_t)((p - 3) * 128 + c0 + col)) * HD;
    uint4 v = *reinterpret_cast<const uint4*>(src + kq * 8);
    *reinterpret_cast<uint4*>(&Bsm[p][col][kq * 8]) = v;
  }
  __syncthreads();

  int arow = row0 + (w << 4) + r;
  int ar = arow < nrows ? arow : nrows - 1;
  const unsigned short* Aa = xaggb + (size_t)ar * HD + q * 8;
  const unsigned short* Ax = xb + (size_t)ar * HD + q * 8;

  f32x4 acc[6][2];
#pragma unroll
  for (int p = 0; p < 6; ++p)
#pragma unroll
    for (int cb = 0; cb < 2; ++cb) acc[p][cb] = (f32x4)0.f;

#pragma unroll
  for (int ks = 0; ks < 4; ++ks) {
    short8 a1 = *reinterpret_cast<const short8*>(Aa + ks * 32);
    short8 a2 = *reinterpret_cast<const short8*>(Ax + ks * 32);
#pragma unroll
    for (int p = 0; p < 6; ++p) {
      short8 af = (p < 3) ? a1 : a2;
#pragma unroll
      for (int cb = 0; cb < 2; ++cb) {
        short8 bf = *reinterpret_cast<const short8*>(&Bsm[p][cb * 16 + r][ks * 32 + q * 8]);
        acc[p][cb] = __builtin_amdgcn_mfma_f32_16x16x32_bf16(af, bf, acc[p][cb], 0, 0, 0);
      }
    }
  }

#pragma unroll
  for (int cb = 0; cb < 2; ++cb) {
    int col = c0 + cb * 16 + r;
    float bir = gbih[col], biz = gbih[col + 128], bin = gbih[col + 256];
    float bhr = gbhh[col], bhz = gbhh[col + 128], bhn = gbhh[col + 256];
#pragma unroll
    for (int reg = 0; reg < 4; ++reg) {
      int row = row0 + (w << 4) + q * 4 + reg;
      if (row < nrows) {
        float ir = acc[0][cb][reg] + bir, iz = acc[1][cb][reg] + biz;
        float inn = acc[2][cb][reg] + bin;
        float hr = acc[3][cb][reg] + bhr, hz = acc[4][cb][reg] + bhz;
        float hn = acc[5][cb][reg] + bhn;
        float rr = sigf(ir + hr), zz = sigf(iz + hz);
        float nn = tanhf(inn + rr * hn);
        float xv = bf2f(xb[(size_t)row * HD + col]);
        hconv[(size_t)row * HD + col] = f2bf((1.f - zz) * nn + zz * xv);
      }
    }
  }
}

// ---------------- fused LSTM ----------------
__global__ __launch_bounds__(256) void lstm_fused_k(
    const unsigned short* __restrict__ hconv, const unsigned short* __restrict__ lwb,
    const float* __restrict__ lbias, float* __restrict__ out, int nrows) {
  __shared__ unsigned short Bsm[3][64][136];
  const int tid = threadIdx.x;
  const int w = tid >> 6, lane = tid & 63;
  const int q = lane >> 4, r = lane & 15;
  const int row0 = blockIdx.y * 64;
  const int c0 = blockIdx.x * 64;

#pragma unroll
  for (int it = 0; it < 12; ++it) {
    int idx = it * 256 + tid;
    int p = idx >> 10, rem = idx & 1023;
    int col = rem >> 4, kq = rem & 15;
    uint4 v = *reinterpret_cast<const uint4*>(
        lwb + ((size_t)(p * 128 + c0 + col)) * HD + kq * 8);
    *reinterpret_cast<uint4*>(&Bsm[p][col][kq * 8]) = v;
  }
  __syncthreads();

  int arow = row0 + (w << 4) + r;
  int ar = arow < nrows ? arow : nrows - 1;
  const unsigned short* Ap = hconv + (size_t)ar * HD + q * 8;

  f32x4 acc[3][4];
#pragma unroll
  for (int p = 0; p < 3; ++p)
#pragma unroll
    for (int cb = 0; cb < 4; ++cb) acc[p][cb] = (f32x4)0.f;

#pragma unroll
  for (int ks = 0; ks < 4; ++ks) {
    short8 af = *reinterpret_cast<const short8*>(Ap + ks * 32);
#pragma unroll
    for (int p = 0; p < 3; ++p)
#pragma unroll
      for (int cb = 0; cb < 4; ++cb) {
        short8 bf = *reinterpret_cast<const short8*>(&Bsm[p][cb * 16 + r][ks * 32 + q * 8]);
        acc[p][cb] = __builtin_amdgcn_mfma_f32_16x16x32_bf16(af, bf, acc[p][cb], 0, 0, 0);
      }
  }

#pragma unroll
  for (int cb = 0; cb < 4; ++cb) {
    int col = c0 + cb * 16 + r;
    float bi = lbias[col], bg = lbias[col + 128], bo = lbias[col + 256];
#pragma unroll
    for (int reg = 0; reg < 4; ++reg) {
      int row = row0 + (w << 4) + q * 4 + reg;
      if (row < nrows) {
        float ig = acc[0][cb][reg] + bi;
        float gg = acc[1][cb][reg] + bg;
        float og = acc[2][cb][reg] + bo;
        float cc = sigf(ig) * tanhf(gg);
        out[(size_t)row * HD + col] = fmaxf(sigf(og) * tanhf(cc), 0.f);
      }
    }
  }
}

// ---------------- host ----------------

extern "C" void kernel_launch(void* const* d_in, const int* in_sizes, int n_in,
                              void* d_out, int out_size, void* d_ws, size_t ws_size,
                              hipStream_t stream) {
  const float* x = (const float*)d_in[0];
  const int* ei = (const int*)d_in[1];
  const float* W = (const float*)d_in[2];
  const float* gw_ih = (const float*)d_in[3];
  const float* gw_hh = (const float*)d_in[4];
  const float* gb_ih = (const float*)d_in[5];
  const float* gb_hh = (const float*)d_in[6];
  const float* lw_ih = (const float*)d_in[7];
  const float* lb_ih = (const float*)d_in[9];
  const float* lb_hh = (const float*)d_in[10];
  float* out = (float*)d_out;

  const int N = in_sizes[0] / HD;
  const int E = in_sizes[1] / 2;
  const size_t nH = (size_t)N * HD;

  int shift = 9;
  while (((N + (1 << shift) - 1) >> shift) > 256) ++shift;
  const int NB = (N + (1 << shift) - 1) >> shift;
  const int sbits = 32 - shift;

  const size_t N4p = (size_t)((N + 1 + 7) & ~7);  // rowstart: N+1
  const size_t E4 = (size_t)((E + 3) & ~3);
  const size_t BC = (size_t)NB * PB + 8;
  const int sc_total = NB * PB;
  const int sc_nblk = (sc_total + SCB - 1) / SCB;

  // ws layout: [rowstart][bcnt][bsums][csr][ebuf|xb][hconv][Bpb][gwhhb][lwb][lbias]
  char* p = (char*)d_ws;
  int* rowstart = (int*)p;  p += 4 * N4p;
  int* bcnt = (int*)p;      p += 4 * BC;
  int* bsums = (int*)p;     p += 4 * 64;
  int* csr = (int*)p;       p += 4 * E4;
  size_t sz_eb = 4 * E4, sz_xb = 2 * nH;
  unsigned* ebuf = (unsigned*)p;            // dead after bfill2_k
  unsigned short* xb = (unsigned short*)p;  // written by convx_k after
  p += (sz_eb > sz_xb ? sz_eb : sz_xb);
  unsigned short* hconv = (unsigned short*)p;  p += 2 * nH;
  unsigned short* Bpb = (unsigned short*)p;    p += 2 * 49152;
  unsigned short* gwhhb = (unsigned short*)p;  p += 2 * 49152;
  unsigned short* lwb = (unsigned short*)p;    p += 2 * 49152;
  float* lbias = (float*)p;                    p += 4 * 384;

  unsigned short* xaggb = (unsigned short*)d_out;  // consumed before out written

  dim3 blk(256);
  unsigned rb = (unsigned)((N + 63) / 64);

  // CSR build (bucketed)
  bcount_k<<<PB, blk, 0, stream>>>(ei, bcnt, E, N, shift, NB);
  scan1_k<<<sc_nblk, blk, 0, stream>>>(bcnt, bsums, sc_total);
  scan2_k<<<1, blk, 0, stream>>>(bsums, sc_nblk);
  scan3_k<<<sc_nblk, blk, 0, stream>>>(bcnt, bsums, sc_total, sc_nblk);
  bpart_k<<<PB, blk, 0, stream>>>(ei, bcnt, ebuf, E, N, shift, NB, sbits);
  bfill2_k<<<NB, blk, 0, stream>>>(ebuf, bcnt, rowstart, csr, N, shift, NB, sbits);

  // conversions + weight folds (xb overwrites ebuf - dead after bfill2)
  convx_k<<<(unsigned)((nH / 4 + 255) / 256), blk, 0, stream>>>(x, xb, (int)(nH / 4));
  prepw_k<<<(2 * 49152 + 384 + 255) / 256, blk, 0, stream>>>(
      gw_hh, lw_ih, lb_ih, lb_hh, gwhhb, lwb, lbias);
  prepbp_k<<<192, blk, 0, stream>>>(W, gw_ih, Bpb);

  // aggregation
  long long gthreads = (long long)N * 64;
  gather_b_k<<<(unsigned)((gthreads + 255) / 256), blk, 0, stream>>>(
      csr, rowstart, xb, xaggb, N);

  // hconv = GRU(xagg, x) with W folded into the input-gate weight
  gru_fused_k<<<dim3(4, rb), blk, 0, stream>>>(
      xaggb, xb, Bpb, gwhhb, gb_ih, gb_hh, hconv, N);

  // out = LSTM(hconv)
  lstm_fused_k<<<dim3(2, rb), blk, 0, stream>>>(hconv, lwb, lbias, out, N);
}